// Round 2
// baseline (73.842 us; speedup 1.0000x reference)
//
#include <hip/hip_runtime.h>
#include <float.h>
#include <math.h>

#define EPS     1e-7f
#define NAN_TO  10.0f
#define THREADS 256
#define TILE    1024                        // matrices per block
#define F4_PER_TILE   ((TILE * 9) / 4)      // 2304 float4 per input array
#define F4_PER_THREAD (F4_PER_TILE / THREADS) // 9

__device__ __forceinline__ float nan_fix(float x) {
    if (isnan(x)) return NAN_TO;
    if (isinf(x)) return x > 0.0f ? FLT_MAX : -FLT_MAX;
    return x;
}

// One KL direction, replicating the reference's float32 op order exactly.
// cov1 = {a1,b1,c1,d1}, cov2 = {a2,b2,c2,d2} (eps already added to diagonals).
__device__ __forceinline__ float kl_dir(float a1, float b1, float c1, float d1,
                                        float a2, float b2, float c2, float d2) {
    #pragma clang fp contract(off)
    float det2 = a2 * d2 - b2 * c2;           // round(a*d) - round(b*c), no FMA
    // cov2_inv = adj / det2, element-wise (matches reference rounding)
    float inv00 =  d2 / det2;
    float inv01 = -b2 / det2;
    float inv10 = -c2 / det2;
    float inv11 =  a2 / det2;
    // einsum('nij,nji->n'): sum_ij inv[i,j] * cov1[j,i], sequential order
    float trace = inv00 * a1;                 // (0,0) * cov1[0,0]
    trace = trace + inv01 * c1;               // (0,1) * cov1[1,0]
    trace = trace + inv10 * b1;               // (1,0) * cov1[0,1]
    trace = trace + inv11 * d1;               // (1,1) * cov1[1,1]

    float det1 = a1 * d1 - b1 * c1;
    float log_term = logf(fmaxf(det2, EPS) / fmaxf(det1, EPS));

    float t = trace - 2.0f;
    t = t + log_term;
    return 0.5f * t;
}

__global__ __launch_bounds__(THREADS)
void skld_kernel(const float* __restrict__ A1,
                 const float* __restrict__ A2,
                 float* __restrict__ out, int N) {
    // 2 * 2304 * 16 B = 73,728 B LDS (gfx950 allows >64 KiB/workgroup)
    __shared__ float4 s1[F4_PER_TILE];
    __shared__ float4 s2[F4_PER_TILE];

    const int t = threadIdx.x;
    const long long mbase = (long long)blockIdx.x * TILE;  // first matrix idx
    const long long fbase = mbase * 9;                     // first float idx

    long long rem = (long long)N - mbase;
    const int cnt = rem < (long long)TILE ? (int)rem : TILE;   // matrices in tile
    const int nf4 = (cnt * 9 + 3) >> 2;                        // float4s to stage

    // fbase = blockIdx.x * 9216, divisible by 4 -> 16B-aligned float4 pointer
    const float4* __restrict__ g1 = (const float4*)(A1 + fbase);
    const float4* __restrict__ g2 = (const float4*)(A2 + fbase);

    #pragma unroll
    for (int i = 0; i < F4_PER_THREAD; ++i) {
        int idx = t + i * THREADS;
        if (idx < nf4) {
            s1[idx] = g1[idx];
            s2[idx] = g2[idx];
        }
    }
    __syncthreads();

    const float* __restrict__ l1 = (const float*)s1;
    const float* __restrict__ l2 = (const float*)s2;

    #pragma unroll
    for (int j = 0; j < TILE / THREADS; ++j) {
        int m = t + j * THREADS;
        if (m < cnt) {
            #pragma clang fp contract(off)
            const int o = m * 9;
            // cov = A[:2,:2] + eps * I  (eps on diagonal only)
            float a1 = l1[o + 0] + EPS;
            float b1 = l1[o + 1];
            float c1 = l1[o + 3];
            float d1 = l1[o + 4] + EPS;
            float a2 = l2[o + 0] + EPS;
            float b2 = l2[o + 1];
            float c2 = l2[o + 3];
            float d2 = l2[o + 4] + EPS;

            float kl12 = nan_fix(kl_dir(a1, b1, c1, d1, a2, b2, c2, d2));
            float kl21 = nan_fix(kl_dir(a2, b2, c2, d2, a1, b1, c1, d1));

            float s = kl12 + kl21;
            out[mbase + m] = s * 0.5f;
        }
    }
}

extern "C" void kernel_launch(void* const* d_in, const int* in_sizes, int n_in,
                              void* d_out, int out_size, void* d_ws, size_t ws_size,
                              hipStream_t stream) {
    const float* A1 = (const float*)d_in[0];
    const float* A2 = (const float*)d_in[1];
    float* out = (float*)d_out;
    const int N = in_sizes[0] / 9;   // 4,000,000
    const int blocks = (N + TILE - 1) / TILE;
    skld_kernel<<<blocks, THREADS, 0, stream>>>(A1, A2, out, N);
}

// Round 4
// 50.897 us; speedup vs baseline: 1.4508x; 1.4508x over previous
//
#include <hip/hip_runtime.h>
#include <float.h>
#include <math.h>

// File-scope: disable FP contraction (FMA fusion) for every function below.
// Needed to match numpy's round(a*d) - round(b*c) determinant bit-exactly;
// FMA-fused det differs by ~1 ulp of |a*d|, amplified by 1/det at tiny det.
#pragma clang fp contract(off)

#define EPS     1e-7f
#define NAN_TO  10.0f
#define THREADS 256

__device__ __forceinline__ float nan_fix(float x) {
    if (isnan(x)) return NAN_TO;
    if (isinf(x)) return x > 0.0f ? FLT_MAX : -FLT_MAX;
    return x;
}

// One KL direction, replicating the reference's float32 op order exactly.
// cov1 = {a1,b1,c1,d1}, cov2 = {a2,b2,c2,d2} (eps already added to diagonals).
__device__ __forceinline__ float kl_dir(float a1, float b1, float c1, float d1,
                                        float a2, float b2, float c2, float d2) {
    float det2 = a2 * d2 - b2 * c2;           // round(a*d) - round(b*c), no FMA
    // cov2_inv = adj / det2, element-wise (matches reference rounding)
    float inv00 =  d2 / det2;
    float inv01 = -b2 / det2;
    float inv10 = -c2 / det2;
    float inv11 =  a2 / det2;
    // einsum('nij,nji->n'): sum_ij inv[i,j] * cov1[j,i], sequential order
    float trace = inv00 * a1;                 // (0,0) * cov1[0,0]
    trace = trace + inv01 * c1;               // (0,1) * cov1[1,0]
    trace = trace + inv10 * b1;               // (1,0) * cov1[0,1]
    trace = trace + inv11 * d1;               // (1,1) * cov1[1,1]

    float det1 = a1 * d1 - b1 * c1;
    float log_term = logf(fmaxf(det2, EPS) / fmaxf(det1, EPS));

    float t = trace - 2.0f;
    t = t + log_term;
    return 0.5f * t;
}

__global__ __launch_bounds__(THREADS, 8)   // 8 waves/SIMD -> VGPR cap 64, 32 waves/CU
void skld_kernel(const float* __restrict__ A1,
                 const float* __restrict__ A2,
                 float* __restrict__ out, int N) {
    const long long m = (long long)blockIdx.x * THREADS + threadIdx.x;
    if (m >= N) return;

    const long long o = m * 9;
    // Need flat offsets {0,1,3,4} of each 9-float record. Consecutive-offset
    // dword loads: each wave instr spans one contiguous 2304B region; the
    // later offsets hit the same L1 lines -> HBM traffic = full stream.
    float a1 = A1[o + 0] + EPS;
    float b1 = A1[o + 1];
    float c1 = A1[o + 3];
    float d1 = A1[o + 4] + EPS;
    float a2 = A2[o + 0] + EPS;
    float b2 = A2[o + 1];
    float c2 = A2[o + 3];
    float d2 = A2[o + 4] + EPS;

    float kl12 = nan_fix(kl_dir(a1, b1, c1, d1, a2, b2, c2, d2));
    float kl21 = nan_fix(kl_dir(a2, b2, c2, d2, a1, b1, c1, d1));

    float s = kl12 + kl21;
    out[m] = s * 0.5f;
}

extern "C" void kernel_launch(void* const* d_in, const int* in_sizes, int n_in,
                              void* d_out, int out_size, void* d_ws, size_t ws_size,
                              hipStream_t stream) {
    const float* A1 = (const float*)d_in[0];
    const float* A2 = (const float*)d_in[1];
    float* out = (float*)d_out;
    const int N = in_sizes[0] / 9;   // 4,000,000
    const int blocks = (N + THREADS - 1) / THREADS;
    skld_kernel<<<blocks, THREADS, 0, stream>>>(A1, A2, out, N);
}